// Round 18
// baseline (149.919 us; speedup 1.0000x reference)
//
#include <hip/hip_runtime.h>
#include <stdint.h>

typedef unsigned short u16;
typedef __attribute__((ext_vector_type(8))) short short8;
typedef __attribute__((ext_vector_type(4))) float f32x4;
typedef __attribute__((ext_vector_type(4))) unsigned short u16x4;
typedef __attribute__((ext_vector_type(4))) unsigned int u32x4;

#define DEVI __device__ __forceinline__

DEVI u16 f2bf(float f) {
  uint32_t u = __builtin_bit_cast(uint32_t, f);
  u += 0x7fffu + ((u >> 16) & 1u);
  return (u16)(u >> 16);
}

DEVI float bf2f(u16 u) {
  uint32_t v = ((uint32_t)u) << 16;
  return __builtin_bit_cast(float, v);
}

DEVI uint32_t cvt_pk_bf16(float lo, float hi) {
  uint32_t r;
  asm("v_cvt_pk_bf16_f32 %0, %1, %2" : "=v"(r) : "v"(lo), "v"(hi));
  return r;
}

DEVI void gload_lds16(const void* g, void* l) {
  __builtin_amdgcn_global_load_lds(
      (const __attribute__((address_space(1))) void*)g,
      (__attribute__((address_space(3))) void*)(uint32_t)(uintptr_t)l,
      16, 0, 0);
}

// ---------------- merged convert: A_cat, W_cat, Wp in one sweep ----------------
__global__ void cvt_all(const float* __restrict__ x, const float* __restrict__ dte,
                        const float* __restrict__ Wqkv, const float* __restrict__ Wdt,
                        const float* __restrict__ Wproj,
                        u16* __restrict__ A_cat, u16* __restrict__ W_cat,
                        u16* __restrict__ Wp) {
  const long T0 = (long)4096 * 2048 / 4;
  const long T1 = (long)3072 * 2048 / 4;
  const long T2 = (long)1024 * 1024 / 4;
  for (long v = (long)blockIdx.x * 256 + threadIdx.x; v < T0 + T1 + T2;
       v += (long)gridDim.x * 256) {
    const float* src;
    u16* dst;
    if (v < T0) {
      const long i = v * 4;
      const long row = i >> 11, c = i & 2047;
      src = (c < 1024) ? (x + row * 1024 + c) : (dte + row * 1024 + (c - 1024));
      dst = A_cat + i;
    } else if (v < T0 + T1) {
      const long i = (v - T0) * 4;
      const long row = i >> 11, c = i & 2047;
      src = (c < 1024) ? (Wqkv + row * 1024 + c) : (Wdt + row * 1024 + (c - 1024));
      dst = W_cat + i;
    } else {
      const long i = (v - T0 - T1) * 4;
      src = Wproj + i;
      dst = Wp + i;
    }
    const float4 f = *(const float4*)src;
    u16x4 o = {f2bf(f.x), f2bf(f.y), f2bf(f.z), f2bf(f.w)};
    *(u16x4*)dst = o;
  }
}

// ------ bf16 GEMM 64x128 tile (m97 schedule + pair-row swizzle), fp32 out ------
__global__ __launch_bounds__(256, 2)
void gemm_bt64(const u16* __restrict__ A, const u16* __restrict__ B,
               float* __restrict__ C, const float* __restrict__ bias1,
               int M, int N, int K) {
  __shared__ u16 As[64 * 32];
  __shared__ u16 Bs[128 * 32];
  const int t = threadIdx.x;
  const int w = t >> 6, l = t & 63;
  const int l15 = l & 15, lg = l >> 4;
  const int bm = blockIdx.x, bn = blockIdx.y;
  const int wr = (w >> 1) * 32, wc = (w & 1) * 64;
  f32x4 acc[2][4] = {};
  const int su = (l & 7) ^ (l >> 3);
  const int rsub = 2 * (l >> 3) + (su >> 2);
  const int sg = su & 3;
  const int sfr = (lg + 4 * (l15 & 1)) ^ (l15 >> 1);
  const int lh = l15 >> 1;

  for (int kt = 0; kt < (K >> 5); ++kt) {
    {
      const int r = w * 16 + rsub;
      gload_lds16(A + (long)(bm * 64 + r) * K + kt * 32 + sg * 8,
                  (char*)As + (w * 8) * 128);
    }
#pragma unroll
    for (int i = 0; i < 2; ++i) {
      const int r = i * 64 + w * 16 + rsub;
      gload_lds16(B + (long)(bn * 128 + r) * K + kt * 32 + sg * 8,
                  (char*)Bs + (i * 32 + w * 8) * 128);
    }
    __syncthreads();
    short8 af[2], bfr[4];
#pragma unroll
    for (int m = 0; m < 2; ++m)
      af[m] = *(const short8*)&As[((w >> 1) * 16 + m * 8 + lh) * 64 + sfr * 8];
#pragma unroll
    for (int n = 0; n < 4; ++n)
      bfr[n] = *(const short8*)&Bs[((w & 1) * 32 + n * 8 + lh) * 64 + sfr * 8];
#pragma unroll
    for (int m = 0; m < 2; ++m)
#pragma unroll
      for (int n = 0; n < 4; ++n)
        acc[m][n] = __builtin_amdgcn_mfma_f32_16x16x32_bf16(af[m], bfr[n], acc[m][n], 0, 0, 0);
    __syncthreads();
  }
#pragma unroll
  for (int m = 0; m < 2; ++m) {
    const int row0 = bm * 64 + wr + m * 16 + lg * 4;
#pragma unroll
    for (int n = 0; n < 4; ++n) {
      const int col = bn * 128 + wc + n * 16 + l15;
      const float bia = bias1 ? bias1[col] : 0.f;
#pragma unroll
      for (int r = 0; r < 4; ++r)
        C[(long)(row0 + r) * N + col] = acc[m][n][r] + bia;
    }
  }
}

// ---- QKV GEMM (m97 schedule + swizzle) writing HEAD-MAJOR raw outputs --------
__global__ __launch_bounds__(256, 2)
void gemm_qkv_hm(const u16* __restrict__ A, const u16* __restrict__ B,
                 const float* __restrict__ bias1, const float* __restrict__ bias2,
                 u16* __restrict__ Qraw, u16* __restrict__ Kraw,
                 u16* __restrict__ Vraw, int M, int N, int K) {
  __shared__ u16 As[128 * 32];
  __shared__ u16 Bs[128 * 32];
  const int t = threadIdx.x;
  const int w = t >> 6, l = t & 63;
  const int l15 = l & 15, lg = l >> 4;
  const int bm = blockIdx.x, bn = blockIdx.y;
  const int wc = (w & 1) * 64;
  const int wrh = (w >> 1) * 32, wch = (w & 1) * 32;
  f32x4 acc[4][4] = {};
  const int su = (l & 7) ^ (l >> 3);
  const int rsub = 2 * (l >> 3) + (su >> 2);
  const int sg = su & 3;
  const int sfr = (lg + 4 * (l15 & 1)) ^ (l15 >> 1);
  const int lh = l15 >> 1;

  for (int kt = 0; kt < (K >> 5); ++kt) {
#pragma unroll
    for (int i = 0; i < 2; ++i) {
      const int r = i * 64 + w * 16 + rsub;
      gload_lds16(A + (long)(bm * 128 + r) * K + kt * 32 + sg * 8,
                  (char*)As + (i * 32 + w * 8) * 128);
      gload_lds16(B + (long)(bn * 128 + r) * K + kt * 32 + sg * 8,
                  (char*)Bs + (i * 32 + w * 8) * 128);
    }
    __syncthreads();
    short8 af[4], bfr[4];
#pragma unroll
    for (int m = 0; m < 4; ++m)
      af[m] = *(const short8*)&As[(wrh + m * 8 + lh) * 64 + sfr * 8];
#pragma unroll
    for (int n = 0; n < 4; ++n)
      bfr[n] = *(const short8*)&Bs[(wch + n * 8 + lh) * 64 + sfr * 8];
#pragma unroll
    for (int m = 0; m < 4; ++m)
#pragma unroll
      for (int n = 0; n < 4; ++n)
        acc[m][n] = __builtin_amdgcn_mfma_f32_16x16x32_bf16(af[m], bfr[n], acc[m][n], 0, 0, 0);
    __syncthreads();
  }
  // head-major epilogue
  u16* Traw = (bn < 8) ? Qraw : (bn < 16) ? Kraw : Vraw;
  const int h = ((bn & 7) << 1) | (wc >> 6);
  const long tb = ((long)((bm >> 3) * 16 + h)) << 16;  // *65536
  const int nnbase = (bm & 7) * 128 + (w >> 1) * 64;
#pragma unroll
  for (int m = 0; m < 4; ++m) {
#pragma unroll
    for (int n = 0; n < 4; ++n) {
      const int col = bn * 128 + wc + n * 16 + l15;
      float bia = bias1[col] + bias2[col];
      const int d = n * 16 + l15;
#pragma unroll
      for (int r = 0; r < 4; ++r) {
        const int nn = nnbase + m * 16 + lg * 4 + r;
        Traw[tb + (long)nn * 64 + d] = f2bf(acc[m][n][r] + bia);
      }
    }
  }
}

// ---- fuse_qk: LN + RoPE for Q and K (no LDS, phase-scoped registers) ---------
// Lane owns chunks [c4*8,+8) and [c4*8+32,+8) of ONE token (4 lanes/token).
__global__ __launch_bounds__(256)
void fuse_qk(const u16* __restrict__ Qraw, const u16* __restrict__ Kraw,
             const float* __restrict__ rope,
             const float* __restrict__ qg, const float* __restrict__ qb,
             const float* __restrict__ kg, const float* __restrict__ kb,
             u16* __restrict__ Q, u16* __restrict__ Ksw) {
  const int t = threadIdx.x, w = t >> 6, l = t & 63;
  const int c4 = l & 3;
  const int tg = l >> 2;
  const int d0 = c4 * 8;
  const int bh = blockIdx.x, ntile = blockIdx.y;
  const int n = ntile * 64 + w * 16 + tg;
  const long obase = (long)bh * 65536 + (long)n * 64;
  const int nx = n & 7;

#define LNROPE_PHASE(SRC, GP, BP, STORE_LO, STORE_HI)                          \
  {                                                                            \
    const short8 xlo = *(const short8*)&SRC[obase + d0];                       \
    const short8 xhi = *(const short8*)&SRC[obase + 32 + d0];                  \
    float vlo[8], vhi[8];                                                      \
    float s = 0.f;                                                             \
    _Pragma("unroll") for (int u = 0; u < 8; ++u) {                            \
      vlo[u] = bf2f((u16)xlo[u]);                                              \
      vhi[u] = bf2f((u16)xhi[u]);                                              \
      s += vlo[u] + vhi[u];                                                    \
    }                                                                          \
    s += __shfl_xor(s, 1); s += __shfl_xor(s, 2);                              \
    const float mean = s * (1.f / 64.f);                                       \
    float vs = 0.f;                                                            \
    _Pragma("unroll") for (int u = 0; u < 8; ++u) {                            \
      vlo[u] -= mean; vhi[u] -= mean;                                          \
      vs += vlo[u] * vlo[u] + vhi[u] * vhi[u];                                 \
    }                                                                          \
    vs += __shfl_xor(vs, 1); vs += __shfl_xor(vs, 2);                          \
    const float rstd = 1.f / sqrtf(vs * (1.f / 64.f) + 1e-5f);                 \
    u32x4 plo, phi;                                                            \
    _Pragma("unroll") for (int p2 = 0; p2 < 2; ++p2) {                         \
      const int db = p2 * 4;                                                   \
      const float4 gl = *(const float4*)&GP[d0 + db];                          \
      const float4 bl = *(const float4*)&BP[d0 + db];                          \
      const float4 gh = *(const float4*)&GP[32 + d0 + db];                     \
      const float4 bhh = *(const float4*)&BP[32 + d0 + db];                    \
      const float4 snl = *(const float4*)&rope[n * 128 + d0 + db];             \
      const float4 snh = *(const float4*)&rope[n * 128 + 32 + d0 + db];        \
      const float4 csl = *(const float4*)&rope[n * 128 + 64 + d0 + db];        \
      const float4 csh = *(const float4*)&rope[n * 128 + 96 + d0 + db];        \
      float ol[4], oh[4];                                                      \
      _Pragma("unroll") for (int u = 0; u < 4; ++u) {                          \
        const float gl_u = ((const float*)&gl)[u], bl_u = ((const float*)&bl)[u]; \
        const float gh_u = ((const float*)&gh)[u], bh_u = ((const float*)&bhh)[u]; \
        const float nl_ = vlo[db + u] * rstd * gl_u + bl_u;                    \
        const float nh_ = vhi[db + u] * rstd * gh_u + bh_u;                    \
        ol[u] = nl_ * ((const float*)&csl)[u] - nh_ * ((const float*)&snl)[u]; \
        oh[u] = nh_ * ((const float*)&csh)[u] + nl_ * ((const float*)&snh)[u]; \
      }                                                                        \
      plo[p2 * 2] = cvt_pk_bf16(ol[0], ol[1]);                                 \
      plo[p2 * 2 + 1] = cvt_pk_bf16(ol[2], ol[3]);                             \
      phi[p2 * 2] = cvt_pk_bf16(oh[0], oh[1]);                                 \
      phi[p2 * 2 + 1] = cvt_pk_bf16(oh[2], oh[3]);                             \
    }                                                                          \
    *(u32x4*)&STORE_LO = plo;                                                  \
    *(u32x4*)&STORE_HI = phi;                                                  \
  }

  LNROPE_PHASE(Qraw, qg, qb, Q[obase + d0], Q[obase + 32 + d0])
  LNROPE_PHASE(Kraw, kg, kb, Ksw[obase + ((c4 ^ nx) * 8)],
               Ksw[obase + (((c4 + 4) ^ nx) * 8)])
#undef LNROPE_PHASE
}

// ---- fuse_v: v-mix + conflict-free transpose -> VTsw -------------------------
// Write transposed-at-write into VlT[64][70] (pitch-70: banks = 24*c4 + 3u +
// tg/2 + const -> all 32 banks, 2-way max). Tail reads rows as 4B-aligned b32.
__global__ __launch_bounds__(256)
void fuse_v(const u16* __restrict__ Vraw, const float* __restrict__ vres,
            const float* __restrict__ pl1, const float* __restrict__ pl2,
            u16* __restrict__ VTsw) {
  __shared__ u16 VlT[64][70];
  const int t = threadIdx.x, w = t >> 6, l = t & 63;
  const int c4 = l & 3;
  const int tg = l >> 2;
  const int d0 = c4 * 8;
  const int bh = blockIdx.x, ntile = blockIdx.y;
  const int n0 = ntile * 64;
  const int tl = w * 16 + tg;
  const int n = n0 + tl;
  const long obase = (long)bh * 65536 + (long)n * 64;
  const float l1 = pl1[0], l2 = pl2[0];

  {
    const short8 xlo = *(const short8*)&Vraw[obase + d0];
    const short8 xhi = *(const short8*)&Vraw[obase + 32 + d0];
    const long vb = ((long)(bh * 1024 + n)) * 64;
    const float4 r0 = *(const float4*)&vres[vb + d0];
    const float4 r1 = *(const float4*)&vres[vb + d0 + 4];
    const float4 r2 = *(const float4*)&vres[vb + 32 + d0];
    const float4 r3 = *(const float4*)&vres[vb + 32 + d0 + 4];
    const float rl[8] = {r0.x, r0.y, r0.z, r0.w, r1.x, r1.y, r1.z, r1.w};
    const float rh[8] = {r2.x, r2.y, r2.z, r2.w, r3.x, r3.y, r3.z, r3.w};
    // transposed scatter: VlT[d][token], conflict-free by pitch-70 derivation
#pragma unroll
    for (int u = 0; u < 8; ++u) {
      VlT[d0 + u][tl] = f2bf(l1 * bf2f((u16)xlo[u]) + l2 * rl[u]);
      VlT[32 + d0 + u][tl] = f2bf(l1 * bf2f((u16)xhi[u]) + l2 * rh[u]);
    }
  }
  __syncthreads();
  // tail: row reads (b32, 4B-aligned, <=2-way) -> scattered 16B VTsw stores
  const uint32_t* base = (const uint32_t*)&VlT[0][0];
#pragma unroll
  for (int i = 0; i < 2; ++i) {
    const int task = i * 256 + t;
    const int dd = task >> 3, cc = task & 7;
    const uint32_t* p = base + dd * 35 + cc * 4;
    u32x4 o = {p[0], p[1], p[2], p[3]};
    *(u32x4*)&VTsw[((long)(bh * 64 + dd)) * 1024 + n0 + ((cc ^ (dd & 7)) * 8)] = o;
  }
}

// -------- flash attention fwd v8: in-register P + KVBLK=128 (round-11) --------
__global__ __launch_bounds__(256, 4)
void attn_fwd8(const u16* __restrict__ Q, const u16* __restrict__ Ksw,
               const u16* __restrict__ VTsw, u16* __restrict__ Out) {
  __shared__ u16 Kl[128 * 64];
  __shared__ u16 Vl[64 * 128];
  const int t = threadIdx.x, w = t >> 6, l = t & 63;
  const int l15 = l & 15, lg = l >> 4;
  const int x7 = l15 & 7;
  const int bh = blockIdx.x, q0 = blockIdx.y * 64;
  const long bo = (long)bh * 65536;
  const bool hihalf = (l & 16) != 0;

  const int qrow = q0 + w * 16 + l15;
  short8 qf[2];
#pragma unroll
  for (int ks = 0; ks < 2; ++ks)
    qf[ks] = *(const short8*)&Q[bo + (long)qrow * 64 + ks * 32 + lg * 8];

  f32x4 acc[4] = {};
  float m_run = -1e30f, l_run = 0.f;

  for (int kb = 0; kb < 8; ++kb) {
    const int kvb = kb * 128;
#pragma unroll
    for (int i = 0; i < 4; ++i) {
      const int idx = i * 256 + t;
      const int krow = idx >> 3, kseg = idx & 7;
      gload_lds16(Ksw + bo + (long)(kvb + krow) * 64 + kseg * 8, (char*)Kl + idx * 16);
      const int vd = idx >> 4, vc = idx & 15;
      gload_lds16(VTsw + bo + (long)vd * 1024 + kvb + vc * 8,
                  (char*)Vl + vd * 256 + vc * 16);
    }
    __syncthreads();
#pragma unroll
    for (int tb = 0; tb < 2; ++tb) {
      f32x4 p[4];
#pragma unroll
      for (int mt = 0; mt < 4; ++mt) {
        f32x4 ps = {};
#pragma unroll
        for (int ks = 0; ks < 2; ++ks) {
          const short8 kf = *(const short8*)&Kl[(tb * 64 + mt * 16 + l15) * 64 +
                                                (((ks * 4 + lg) ^ x7) * 8)];
          ps = __builtin_amdgcn_mfma_f32_16x16x32_bf16(kf, qf[ks], ps, 0, 0, 0);
        }
        p[mt] = ps;
      }
      float mx = p[0][0];
#pragma unroll
      for (int mt = 0; mt < 4; ++mt)
#pragma unroll
        for (int r = 0; r < 4; ++r) mx = fmaxf(mx, p[mt][r]);
      mx = fmaxf(mx, __shfl_xor(mx, 16));
      mx = fmaxf(mx, __shfl_xor(mx, 32));
      const float mnew = fmaxf(m_run, mx * 0.125f);
      const float alpha = __expf(m_run - mnew);
      m_run = mnew;
      float sum = 0.f;
#pragma unroll
      for (int mt = 0; mt < 4; ++mt)
#pragma unroll
        for (int r = 0; r < 4; ++r) {
          const float e = __expf(p[mt][r] * 0.125f - mnew);
          p[mt][r] = e;
          sum += e;
        }
      sum += __shfl_xor(sum, 16);
      sum += __shfl_xor(sum, 32);
      l_run = l_run * alpha + sum;
      uint32_t u0[4], u1[4];
#pragma unroll
      for (int mt = 0; mt < 4; ++mt) {
        u0[mt] = cvt_pk_bf16(p[mt][0], p[mt][1]);
        u1[mt] = cvt_pk_bf16(p[mt][2], p[mt][3]);
      }
#pragma unroll
      for (int mt = 0; mt < 4; ++mt)
#pragma unroll
        for (int r = 0; r < 4; ++r) acc[mt][r] *= alpha;
#pragma unroll
      for (int ks = 0; ks < 2; ++ks) {
        uint32_t X0 = u0[2 * ks], Y0 = u0[2 * ks + 1];
        asm("v_permlane32_swap_b32 %0, %1" : "+v"(X0), "+v"(Y0));
        uint32_t X1 = u1[2 * ks], Y1 = u1[2 * ks + 1];
        asm("v_permlane32_swap_b32 %0, %1" : "+v"(X1), "+v"(Y1));
        const uint32_t Xs0 = (uint32_t)__shfl_xor((int)X0, 16);
        const uint32_t Ys0 = (uint32_t)__shfl_xor((int)Y0, 16);
        const uint32_t Xs1 = (uint32_t)__shfl_xor((int)X1, 16);
        const uint32_t Ys1 = (uint32_t)__shfl_xor((int)Y1, 16);
        u32x4 pv;
        pv[0] = hihalf ? Ys0 : X0;
        pv[1] = hihalf ? Ys1 : X1;
        pv[2] = hihalf ? Y0 : Xs0;
        pv[3] = hihalf ? Y1 : Xs1;
        const short8 pf = __builtin_bit_cast(short8, pv);
#pragma unroll
        for (int mt = 0; mt < 4; ++mt) {
          const short8 vf = *(const short8*)&Vl[(mt * 16 + l15) * 128 + tb * 64 +
                                                (((ks * 4 + lg) ^ x7) * 8)];
          acc[mt] = __builtin_amdgcn_mfma_f32_16x16x32_bf16(vf, pf, acc[mt], 0, 0, 0);
        }
      }
    }
    __syncthreads();
  }
  const int b = bh >> 4, h = bh & 15;
  const float inv = 1.f / l_run;
  const long obase = ((long)(b * 1024 + qrow)) * 1024 + h * 64;
#pragma unroll
  for (int mt = 0; mt < 4; ++mt) {
    const long o = obase + mt * 16 + lg * 4;
    *(uint32_t*)&Out[o] = cvt_pk_bf16(acc[mt][0] * inv, acc[mt][1] * inv);
    *(uint32_t*)&Out[o + 2] = cvt_pk_bf16(acc[mt][2] * inv, acc[mt][3] * inv);
  }
}

extern "C" void kernel_launch(void* const* d_in, const int* in_sizes, int n_in,
                              void* d_out, int out_size, void* d_ws, size_t ws_size,
                              hipStream_t stream) {
  const float* x     = (const float*)d_in[0];
  const float* rope  = (const float*)d_in[1];
  const float* dte   = (const float*)d_in[2];
  const float* vres  = (const float*)d_in[3];
  const float* Wqkv  = (const float*)d_in[4];
  const float* bqkv  = (const float*)d_in[5];
  const float* Wdt   = (const float*)d_in[6];
  const float* bdt   = (const float*)d_in[7];
  const float* qn_g  = (const float*)d_in[8];
  const float* qn_b  = (const float*)d_in[9];
  const float* kn_g  = (const float*)d_in[10];
  const float* kn_b  = (const float*)d_in[11];
  const float* l1    = (const float*)d_in[12];
  const float* l2    = (const float*)d_in[13];
  const float* Wproj = (const float*)d_in[14];
  const float* bproj = (const float*)d_in[15];
  float* out = (float*)d_out;

  char* ws = (char*)d_ws;
  u16*   A_cat = (u16*)(ws);                    // [4096,2048] bf16
  u16*   W_cat = (u16*)(ws + 16777216);         // [3072,2048] bf16
  u16*   Wp    = (u16*)(ws + 29360128);         // [1024,1024] bf16
  u16*   Qraw  = (u16*)(ws + 31457280);         // [64,1024,64] bf16 head-major
  u16*   Kraw  = (u16*)(ws + 39845888);
  u16*   Vraw  = (u16*)(ws + 48234496);
  u16*   Qb    = (u16*)(ws + 56623104);         // [64,1024,64] bf16
  u16*   Ksw   = (u16*)(ws + 65011712);         // swizzled K
  u16*   VTsw  = (u16*)(ws + 73400320);         // swizzled V^T
  u16*   AO    = (u16*)(ws + 81788928);         // [4096,1024] bf16
  // total ws usage: 90,177,536 bytes

  cvt_all<<<2048, 256, 0, stream>>>(x, dte, Wqkv, Wdt, Wproj, A_cat, W_cat, Wp);
  gemm_qkv_hm<<<dim3(32, 24), 256, 0, stream>>>(A_cat, W_cat, bqkv, bdt,
                                                Qraw, Kraw, Vraw, 4096, 3072, 2048);
  fuse_qk<<<dim3(64, 16), 256, 0, stream>>>(Qraw, Kraw, rope, qn_g, qn_b,
                                            kn_g, kn_b, Qb, Ksw);
  fuse_v<<<dim3(64, 16), 256, 0, stream>>>(Vraw, vres, l1, l2, VTsw);
  attn_fwd8<<<dim3(64, 16), 256, 0, stream>>>(Qb, Ksw, VTsw, AO);
  gemm_bt64<<<dim3(64, 8), 256, 0, stream>>>(AO, Wp, out, bproj, 4096, 1024, 1024);
}

// Round 19
// 146.220 us; speedup vs baseline: 1.0253x; 1.0253x over previous
//
#include <hip/hip_runtime.h>
#include <stdint.h>

typedef unsigned short u16;
typedef __attribute__((ext_vector_type(8))) short short8;
typedef __attribute__((ext_vector_type(4))) float f32x4;
typedef __attribute__((ext_vector_type(4))) unsigned short u16x4;
typedef __attribute__((ext_vector_type(4))) unsigned int u32x4;

#define DEVI __device__ __forceinline__

DEVI u16 f2bf(float f) {
  uint32_t u = __builtin_bit_cast(uint32_t, f);
  u += 0x7fffu + ((u >> 16) & 1u);
  return (u16)(u >> 16);
}

DEVI float bf2f(u16 u) {
  uint32_t v = ((uint32_t)u) << 16;
  return __builtin_bit_cast(float, v);
}

DEVI uint32_t cvt_pk_bf16(float lo, float hi) {
  uint32_t r;
  asm("v_cvt_pk_bf16_f32 %0, %1, %2" : "=v"(r) : "v"(lo), "v"(hi));
  return r;
}

DEVI void gload_lds16(const void* g, void* l) {
  __builtin_amdgcn_global_load_lds(
      (const __attribute__((address_space(1))) void*)g,
      (__attribute__((address_space(3))) void*)(uint32_t)(uintptr_t)l,
      16, 0, 0);
}

// ---------------- merged convert: A_cat, W_cat, Wp in one sweep ----------------
__global__ void cvt_all(const float* __restrict__ x, const float* __restrict__ dte,
                        const float* __restrict__ Wqkv, const float* __restrict__ Wdt,
                        const float* __restrict__ Wproj,
                        u16* __restrict__ A_cat, u16* __restrict__ W_cat,
                        u16* __restrict__ Wp) {
  const long T0 = (long)4096 * 2048 / 4;
  const long T1 = (long)3072 * 2048 / 4;
  const long T2 = (long)1024 * 1024 / 4;
  for (long v = (long)blockIdx.x * 256 + threadIdx.x; v < T0 + T1 + T2;
       v += (long)gridDim.x * 256) {
    const float* src;
    u16* dst;
    if (v < T0) {
      const long i = v * 4;
      const long row = i >> 11, c = i & 2047;
      src = (c < 1024) ? (x + row * 1024 + c) : (dte + row * 1024 + (c - 1024));
      dst = A_cat + i;
    } else if (v < T0 + T1) {
      const long i = (v - T0) * 4;
      const long row = i >> 11, c = i & 2047;
      src = (c < 1024) ? (Wqkv + row * 1024 + c) : (Wdt + row * 1024 + (c - 1024));
      dst = W_cat + i;
    } else {
      const long i = (v - T0 - T1) * 4;
      src = Wproj + i;
      dst = Wp + i;
    }
    const float4 f = *(const float4*)src;
    u16x4 o = {f2bf(f.x), f2bf(f.y), f2bf(f.z), f2bf(f.w)};
    *(u16x4*)dst = o;
  }
}

// ------ bf16 GEMM 64x128 tile (m97 schedule + pair-row swizzle), fp32 out ------
__global__ __launch_bounds__(256, 2)
void gemm_bt64(const u16* __restrict__ A, const u16* __restrict__ B,
               float* __restrict__ C, const float* __restrict__ bias1,
               int M, int N, int K) {
  __shared__ u16 As[64 * 32];
  __shared__ u16 Bs[128 * 32];
  const int t = threadIdx.x;
  const int w = t >> 6, l = t & 63;
  const int l15 = l & 15, lg = l >> 4;
  const int bm = blockIdx.x, bn = blockIdx.y;
  const int wr = (w >> 1) * 32, wc = (w & 1) * 64;
  f32x4 acc[2][4] = {};
  const int su = (l & 7) ^ (l >> 3);
  const int rsub = 2 * (l >> 3) + (su >> 2);
  const int sg = su & 3;
  const int sfr = (lg + 4 * (l15 & 1)) ^ (l15 >> 1);
  const int lh = l15 >> 1;

  for (int kt = 0; kt < (K >> 5); ++kt) {
    {
      const int r = w * 16 + rsub;
      gload_lds16(A + (long)(bm * 64 + r) * K + kt * 32 + sg * 8,
                  (char*)As + (w * 8) * 128);
    }
#pragma unroll
    for (int i = 0; i < 2; ++i) {
      const int r = i * 64 + w * 16 + rsub;
      gload_lds16(B + (long)(bn * 128 + r) * K + kt * 32 + sg * 8,
                  (char*)Bs + (i * 32 + w * 8) * 128);
    }
    __syncthreads();
    short8 af[2], bfr[4];
#pragma unroll
    for (int m = 0; m < 2; ++m)
      af[m] = *(const short8*)&As[((w >> 1) * 16 + m * 8 + lh) * 64 + sfr * 8];
#pragma unroll
    for (int n = 0; n < 4; ++n)
      bfr[n] = *(const short8*)&Bs[((w & 1) * 32 + n * 8 + lh) * 64 + sfr * 8];
#pragma unroll
    for (int m = 0; m < 2; ++m)
#pragma unroll
      for (int n = 0; n < 4; ++n)
        acc[m][n] = __builtin_amdgcn_mfma_f32_16x16x32_bf16(af[m], bfr[n], acc[m][n], 0, 0, 0);
    __syncthreads();
  }
#pragma unroll
  for (int m = 0; m < 2; ++m) {
    const int row0 = bm * 64 + wr + m * 16 + lg * 4;
#pragma unroll
    for (int n = 0; n < 4; ++n) {
      const int col = bn * 128 + wc + n * 16 + l15;
      const float bia = bias1 ? bias1[col] : 0.f;
#pragma unroll
      for (int r = 0; r < 4; ++r)
        C[(long)(row0 + r) * N + col] = acc[m][n][r] + bia;
    }
  }
}

// ---- QKV GEMM (m97 schedule + swizzle) writing HEAD-MAJOR raw outputs --------
__global__ __launch_bounds__(256, 2)
void gemm_qkv_hm(const u16* __restrict__ A, const u16* __restrict__ B,
                 const float* __restrict__ bias1, const float* __restrict__ bias2,
                 u16* __restrict__ Qraw, u16* __restrict__ Kraw,
                 u16* __restrict__ Vraw, int M, int N, int K) {
  __shared__ u16 As[128 * 32];
  __shared__ u16 Bs[128 * 32];
  const int t = threadIdx.x;
  const int w = t >> 6, l = t & 63;
  const int l15 = l & 15, lg = l >> 4;
  const int bm = blockIdx.x, bn = blockIdx.y;
  const int wc = (w & 1) * 64;
  const int wrh = (w >> 1) * 32, wch = (w & 1) * 32;
  f32x4 acc[4][4] = {};
  const int su = (l & 7) ^ (l >> 3);
  const int rsub = 2 * (l >> 3) + (su >> 2);
  const int sg = su & 3;
  const int sfr = (lg + 4 * (l15 & 1)) ^ (l15 >> 1);
  const int lh = l15 >> 1;

  for (int kt = 0; kt < (K >> 5); ++kt) {
#pragma unroll
    for (int i = 0; i < 2; ++i) {
      const int r = i * 64 + w * 16 + rsub;
      gload_lds16(A + (long)(bm * 128 + r) * K + kt * 32 + sg * 8,
                  (char*)As + (i * 32 + w * 8) * 128);
      gload_lds16(B + (long)(bn * 128 + r) * K + kt * 32 + sg * 8,
                  (char*)Bs + (i * 32 + w * 8) * 128);
    }
    __syncthreads();
    short8 af[4], bfr[4];
#pragma unroll
    for (int m = 0; m < 4; ++m)
      af[m] = *(const short8*)&As[(wrh + m * 8 + lh) * 64 + sfr * 8];
#pragma unroll
    for (int n = 0; n < 4; ++n)
      bfr[n] = *(const short8*)&Bs[(wch + n * 8 + lh) * 64 + sfr * 8];
#pragma unroll
    for (int m = 0; m < 4; ++m)
#pragma unroll
      for (int n = 0; n < 4; ++n)
        acc[m][n] = __builtin_amdgcn_mfma_f32_16x16x32_bf16(af[m], bfr[n], acc[m][n], 0, 0, 0);
    __syncthreads();
  }
  // head-major epilogue
  u16* Traw = (bn < 8) ? Qraw : (bn < 16) ? Kraw : Vraw;
  const int h = ((bn & 7) << 1) | (wc >> 6);
  const long tb = ((long)((bm >> 3) * 16 + h)) << 16;  // *65536
  const int nnbase = (bm & 7) * 128 + (w >> 1) * 64;
#pragma unroll
  for (int m = 0; m < 4; ++m) {
#pragma unroll
    for (int n = 0; n < 4; ++n) {
      const int col = bn * 128 + wc + n * 16 + l15;
      float bia = bias1[col] + bias2[col];
      const int d = n * 16 + l15;
#pragma unroll
      for (int r = 0; r < 4; ++r) {
        const int nn = nnbase + m * 16 + lg * 4 + r;
        Traw[tb + (long)nn * 64 + d] = f2bf(acc[m][n][r] + bia);
      }
    }
  }
}

// ---- fuse_kv: K LN+RoPE -> Ksw, V mix -> VTsw (r16 fuse_qkv4 minus Q) --------
__global__ __launch_bounds__(256)
void fuse_kv(const u16* __restrict__ Kraw, const u16* __restrict__ Vraw,
             const float* __restrict__ vres, const float* __restrict__ rope,
             const float* __restrict__ kg, const float* __restrict__ kb,
             const float* __restrict__ pl1, const float* __restrict__ pl2,
             u16* __restrict__ Ksw, u16* __restrict__ VTsw) {
  __shared__ u16 Vl[64][72];
  const int t = threadIdx.x, w = t >> 6, l = t & 63;
  const int c4 = l & 3;
  const int tg = l >> 2;
  const int d0 = c4 * 8;
  const int bh = blockIdx.x, ntile = blockIdx.y;
  const int n0 = ntile * 64;
  const int tl = w * 16 + tg;
  const int n = n0 + tl;
  const long obase = (long)bh * 65536 + (long)n * 64;
  const int nx = n & 7;

  // ---- K phase: LN + RoPE ----
  {
    const short8 xlo = *(const short8*)&Kraw[obase + d0];
    const short8 xhi = *(const short8*)&Kraw[obase + 32 + d0];
    float vlo[8], vhi[8];
    float s = 0.f;
#pragma unroll
    for (int u = 0; u < 8; ++u) {
      vlo[u] = bf2f((u16)xlo[u]);
      vhi[u] = bf2f((u16)xhi[u]);
      s += vlo[u] + vhi[u];
    }
    s += __shfl_xor(s, 1); s += __shfl_xor(s, 2);
    const float mean = s * (1.f / 64.f);
    float vs = 0.f;
#pragma unroll
    for (int u = 0; u < 8; ++u) {
      vlo[u] -= mean; vhi[u] -= mean;
      vs += vlo[u] * vlo[u] + vhi[u] * vhi[u];
    }
    vs += __shfl_xor(vs, 1); vs += __shfl_xor(vs, 2);
    const float rstd = 1.f / sqrtf(vs * (1.f / 64.f) + 1e-5f);
    u32x4 plo, phi;
#pragma unroll
    for (int p2 = 0; p2 < 2; ++p2) {
      const int db = p2 * 4;
      const float4 gl = *(const float4*)&kg[d0 + db];
      const float4 bl = *(const float4*)&kb[d0 + db];
      const float4 gh = *(const float4*)&kg[32 + d0 + db];
      const float4 bhh = *(const float4*)&kb[32 + d0 + db];
      const float4 snl = *(const float4*)&rope[n * 128 + d0 + db];
      const float4 snh = *(const float4*)&rope[n * 128 + 32 + d0 + db];
      const float4 csl = *(const float4*)&rope[n * 128 + 64 + d0 + db];
      const float4 csh = *(const float4*)&rope[n * 128 + 96 + d0 + db];
      float ol[4], oh[4];
#pragma unroll
      for (int u = 0; u < 4; ++u) {
        const float nl_ = vlo[db + u] * rstd * ((const float*)&gl)[u] + ((const float*)&bl)[u];
        const float nh_ = vhi[db + u] * rstd * ((const float*)&gh)[u] + ((const float*)&bhh)[u];
        ol[u] = nl_ * ((const float*)&csl)[u] - nh_ * ((const float*)&snl)[u];
        oh[u] = nh_ * ((const float*)&csh)[u] + nl_ * ((const float*)&snh)[u];
      }
      plo[p2 * 2] = cvt_pk_bf16(ol[0], ol[1]);
      plo[p2 * 2 + 1] = cvt_pk_bf16(ol[2], ol[3]);
      phi[p2 * 2] = cvt_pk_bf16(oh[0], oh[1]);
      phi[p2 * 2 + 1] = cvt_pk_bf16(oh[2], oh[3]);
    }
    *(u32x4*)&Ksw[obase + ((c4 ^ nx) * 8)] = plo;
    *(u32x4*)&Ksw[obase + (((c4 + 4) ^ nx) * 8)] = phi;
  }

  // ---- V phase ----
  {
    const float l1 = pl1[0], l2 = pl2[0];
    const short8 xlo = *(const short8*)&Vraw[obase + d0];
    const short8 xhi = *(const short8*)&Vraw[obase + 32 + d0];
    const long vb = ((long)(bh * 1024 + n)) * 64;
    const float4 r0 = *(const float4*)&vres[vb + d0];
    const float4 r1 = *(const float4*)&vres[vb + d0 + 4];
    const float4 r2 = *(const float4*)&vres[vb + 32 + d0];
    const float4 r3 = *(const float4*)&vres[vb + 32 + d0 + 4];
    const float rl[8] = {r0.x, r0.y, r0.z, r0.w, r1.x, r1.y, r1.z, r1.w};
    const float rh[8] = {r2.x, r2.y, r2.z, r2.w, r3.x, r3.y, r3.z, r3.w};
    u32x4 plo, phi;
#pragma unroll
    for (int u = 0; u < 4; ++u) {
      plo[u] = cvt_pk_bf16(l1 * bf2f((u16)xlo[2 * u]) + l2 * rl[2 * u],
                           l1 * bf2f((u16)xlo[2 * u + 1]) + l2 * rl[2 * u + 1]);
      phi[u] = cvt_pk_bf16(l1 * bf2f((u16)xhi[2 * u]) + l2 * rh[2 * u],
                           l1 * bf2f((u16)xhi[2 * u + 1]) + l2 * rh[2 * u + 1]);
    }
    *(u32x4*)&Vl[tl][d0] = plo;
    *(u32x4*)&Vl[tl][32 + d0] = phi;
  }
  __syncthreads();
  // transpose-write V^T (chunk-swizzled per 64-n tile) — proven tail
#pragma unroll
  for (int i = 0; i < 2; ++i) {
    const int task = i * 256 + t;
    const int dd = task >> 3, cc = task & 7;
    short8 o;
#pragma unroll
    for (int u = 0; u < 8; ++u) o[u] = (short)Vl[cc * 8 + u][dd];
    *(short8*)&VTsw[((long)(bh * 64 + dd)) * 1024 + n0 + ((cc ^ (dd & 7)) * 8)] = o;
  }
}

// -------- flash attention fwd v9: Q LN+RoPE in prologue (reads Qraw) ----------
// Lane (w,l15,lg) holds q-row (q0+w*16+l15), d in [lg*8,+8) u [32+lg*8,+8).
// LN reduces over the row's 4 lanes (shfl_xor 16/32); rotate-half partner is
// the other ks register (in-lane). Loop body identical to proven attn_fwd8.
__global__ __launch_bounds__(256, 4)
void attn_fwd9(const u16* __restrict__ Qraw, const u16* __restrict__ Ksw,
               const u16* __restrict__ VTsw, const float* __restrict__ rope,
               const float* __restrict__ qg, const float* __restrict__ qb,
               u16* __restrict__ Out) {
  __shared__ u16 Kl[128 * 64];
  __shared__ u16 Vl[64 * 128];
  const int t = threadIdx.x, w = t >> 6, l = t & 63;
  const int l15 = l & 15, lg = l >> 4;
  const int x7 = l15 & 7;
  const int bh = blockIdx.x, q0 = blockIdx.y * 64;
  const long bo = (long)bh * 65536;
  const bool hihalf = (l & 16) != 0;

  const int qrow = q0 + w * 16 + l15;
  // ---- prologue: Q LN + RoPE in-register ----
  short8 qf[2];
  {
    const int dq = lg * 8;
    const long qb_ = bo + (long)qrow * 64;
    const short8 x0 = *(const short8*)&Qraw[qb_ + dq];
    const short8 x1 = *(const short8*)&Qraw[qb_ + 32 + dq];
    float v0[8], v1[8];
    float s = 0.f;
#pragma unroll
    for (int u = 0; u < 8; ++u) {
      v0[u] = bf2f((u16)x0[u]);
      v1[u] = bf2f((u16)x1[u]);
      s += v0[u] + v1[u];
    }
    s += __shfl_xor(s, 16); s += __shfl_xor(s, 32);
    const float mean = s * (1.f / 64.f);
    float vs = 0.f;
#pragma unroll
    for (int u = 0; u < 8; ++u) {
      v0[u] -= mean; v1[u] -= mean;
      vs += v0[u] * v0[u] + v1[u] * v1[u];
    }
    vs += __shfl_xor(vs, 16); vs += __shfl_xor(vs, 32);
    const float rstd = 1.f / sqrtf(vs * (1.f / 64.f) + 1e-5f);
    u32x4 p0, p1;
#pragma unroll
    for (int p2 = 0; p2 < 2; ++p2) {
      const int db = p2 * 4;
      const float4 gl = *(const float4*)&qg[dq + db];
      const float4 bl = *(const float4*)&qb[dq + db];
      const float4 gh = *(const float4*)&qg[32 + dq + db];
      const float4 bhh = *(const float4*)&qb[32 + dq + db];
      const float4 snl = *(const float4*)&rope[qrow * 128 + dq + db];
      const float4 snh = *(const float4*)&rope[qrow * 128 + 32 + dq + db];
      const float4 csl = *(const float4*)&rope[qrow * 128 + 64 + dq + db];
      const float4 csh = *(const float4*)&rope[qrow * 128 + 96 + dq + db];
      float ol[4], oh[4];
#pragma unroll
      for (int u = 0; u < 4; ++u) {
        const float nl_ = v0[db + u] * rstd * ((const float*)&gl)[u] + ((const float*)&bl)[u];
        const float nh_ = v1[db + u] * rstd * ((const float*)&gh)[u] + ((const float*)&bhh)[u];
        ol[u] = nl_ * ((const float*)&csl)[u] - nh_ * ((const float*)&snl)[u];
        oh[u] = nh_ * ((const float*)&csh)[u] + nl_ * ((const float*)&snh)[u];
      }
      p0[p2 * 2] = cvt_pk_bf16(ol[0], ol[1]);
      p0[p2 * 2 + 1] = cvt_pk_bf16(ol[2], ol[3]);
      p1[p2 * 2] = cvt_pk_bf16(oh[0], oh[1]);
      p1[p2 * 2 + 1] = cvt_pk_bf16(oh[2], oh[3]);
    }
    qf[0] = __builtin_bit_cast(short8, p0);
    qf[1] = __builtin_bit_cast(short8, p1);
  }

  f32x4 acc[4] = {};
  float m_run = -1e30f, l_run = 0.f;

  for (int kb = 0; kb < 8; ++kb) {
    const int kvb = kb * 128;
#pragma unroll
    for (int i = 0; i < 4; ++i) {
      const int idx = i * 256 + t;
      const int krow = idx >> 3, kseg = idx & 7;
      gload_lds16(Ksw + bo + (long)(kvb + krow) * 64 + kseg * 8, (char*)Kl + idx * 16);
      const int vd = idx >> 4, vc = idx & 15;
      gload_lds16(VTsw + bo + (long)vd * 1024 + kvb + vc * 8,
                  (char*)Vl + vd * 256 + vc * 16);
    }
    __syncthreads();
#pragma unroll
    for (int tb = 0; tb < 2; ++tb) {
      f32x4 p[4];
#pragma unroll
      for (int mt = 0; mt < 4; ++mt) {
        f32x4 ps = {};
#pragma unroll
        for (int ks = 0; ks < 2; ++ks) {
          const short8 kf = *(const short8*)&Kl[(tb * 64 + mt * 16 + l15) * 64 +
                                                (((ks * 4 + lg) ^ x7) * 8)];
          ps = __builtin_amdgcn_mfma_f32_16x16x32_bf16(kf, qf[ks], ps, 0, 0, 0);
        }
        p[mt] = ps;
      }
      float mx = p[0][0];
#pragma unroll
      for (int mt = 0; mt < 4; ++mt)
#pragma unroll
        for (int r = 0; r < 4; ++r) mx = fmaxf(mx, p[mt][r]);
      mx = fmaxf(mx, __shfl_xor(mx, 16));
      mx = fmaxf(mx, __shfl_xor(mx, 32));
      const float mnew = fmaxf(m_run, mx * 0.125f);
      const float alpha = __expf(m_run - mnew);
      m_run = mnew;
      float sum = 0.f;
#pragma unroll
      for (int mt = 0; mt < 4; ++mt)
#pragma unroll
        for (int r = 0; r < 4; ++r) {
          const float e = __expf(p[mt][r] * 0.125f - mnew);
          p[mt][r] = e;
          sum += e;
        }
      sum += __shfl_xor(sum, 16);
      sum += __shfl_xor(sum, 32);
      l_run = l_run * alpha + sum;
      uint32_t u0[4], u1[4];
#pragma unroll
      for (int mt = 0; mt < 4; ++mt) {
        u0[mt] = cvt_pk_bf16(p[mt][0], p[mt][1]);
        u1[mt] = cvt_pk_bf16(p[mt][2], p[mt][3]);
      }
#pragma unroll
      for (int mt = 0; mt < 4; ++mt)
#pragma unroll
        for (int r = 0; r < 4; ++r) acc[mt][r] *= alpha;
#pragma unroll
      for (int ks = 0; ks < 2; ++ks) {
        uint32_t X0 = u0[2 * ks], Y0 = u0[2 * ks + 1];
        asm("v_permlane32_swap_b32 %0, %1" : "+v"(X0), "+v"(Y0));
        uint32_t X1 = u1[2 * ks], Y1 = u1[2 * ks + 1];
        asm("v_permlane32_swap_b32 %0, %1" : "+v"(X1), "+v"(Y1));
        const uint32_t Xs0 = (uint32_t)__shfl_xor((int)X0, 16);
        const uint32_t Ys0 = (uint32_t)__shfl_xor((int)Y0, 16);
        const uint32_t Xs1 = (uint32_t)__shfl_xor((int)X1, 16);
        const uint32_t Ys1 = (uint32_t)__shfl_xor((int)Y1, 16);
        u32x4 pv;
        pv[0] = hihalf ? Ys0 : X0;
        pv[1] = hihalf ? Ys1 : X1;
        pv[2] = hihalf ? Y0 : Xs0;
        pv[3] = hihalf ? Y1 : Xs1;
        const short8 pf = __builtin_bit_cast(short8, pv);
#pragma unroll
        for (int mt = 0; mt < 4; ++mt) {
          const short8 vf = *(const short8*)&Vl[(mt * 16 + l15) * 128 + tb * 64 +
                                                (((ks * 4 + lg) ^ x7) * 8)];
          acc[mt] = __builtin_amdgcn_mfma_f32_16x16x32_bf16(vf, pf, acc[mt], 0, 0, 0);
        }
      }
    }
    __syncthreads();
  }
  const int b = bh >> 4, h = bh & 15;
  const float inv = 1.f / l_run;
  const long obase = ((long)(b * 1024 + qrow)) * 1024 + h * 64;
#pragma unroll
  for (int mt = 0; mt < 4; ++mt) {
    const long o = obase + mt * 16 + lg * 4;
    *(uint32_t*)&Out[o] = cvt_pk_bf16(acc[mt][0] * inv, acc[mt][1] * inv);
    *(uint32_t*)&Out[o + 2] = cvt_pk_bf16(acc[mt][2] * inv, acc[mt][3] * inv);
  }
}

extern "C" void kernel_launch(void* const* d_in, const int* in_sizes, int n_in,
                              void* d_out, int out_size, void* d_ws, size_t ws_size,
                              hipStream_t stream) {
  const float* x     = (const float*)d_in[0];
  const float* rope  = (const float*)d_in[1];
  const float* dte   = (const float*)d_in[2];
  const float* vres  = (const float*)d_in[3];
  const float* Wqkv  = (const float*)d_in[4];
  const float* bqkv  = (const float*)d_in[5];
  const float* Wdt   = (const float*)d_in[6];
  const float* bdt   = (const float*)d_in[7];
  const float* qn_g  = (const float*)d_in[8];
  const float* qn_b  = (const float*)d_in[9];
  const float* kn_g  = (const float*)d_in[10];
  const float* kn_b  = (const float*)d_in[11];
  const float* l1    = (const float*)d_in[12];
  const float* l2    = (const float*)d_in[13];
  const float* Wproj = (const float*)d_in[14];
  const float* bproj = (const float*)d_in[15];
  float* out = (float*)d_out;

  char* ws = (char*)d_ws;
  u16*   A_cat = (u16*)(ws);                    // [4096,2048] bf16
  u16*   W_cat = (u16*)(ws + 16777216);         // [3072,2048] bf16
  u16*   Wp    = (u16*)(ws + 29360128);         // [1024,1024] bf16
  u16*   Qraw  = (u16*)(ws + 31457280);         // [64,1024,64] bf16 head-major
  u16*   Kraw  = (u16*)(ws + 39845888);
  u16*   Vraw  = (u16*)(ws + 48234496);
  u16*   Ksw   = (u16*)(ws + 65011712);         // swizzled K
  u16*   VTsw  = (u16*)(ws + 73400320);         // swizzled V^T
  u16*   AO    = (u16*)(ws + 81788928);         // [4096,1024] bf16
  // total ws usage: 90,177,536 bytes

  cvt_all<<<2048, 256, 0, stream>>>(x, dte, Wqkv, Wdt, Wproj, A_cat, W_cat, Wp);
  gemm_qkv_hm<<<dim3(32, 24), 256, 0, stream>>>(A_cat, W_cat, bqkv, bdt,
                                                Qraw, Kraw, Vraw, 4096, 3072, 2048);
  fuse_kv<<<dim3(64, 16), 256, 0, stream>>>(Kraw, Vraw, vres, rope, kn_g, kn_b,
                                            l1, l2, Ksw, VTsw);
  attn_fwd9<<<dim3(64, 16), 256, 0, stream>>>(Qraw, Ksw, VTsw, rope, qn_g, qn_b, AO);
  gemm_bt64<<<dim3(64, 8), 256, 0, stream>>>(AO, Wp, out, bproj, 4096, 1024, 1024);
}